// Round 1
// baseline (1403.774 us; speedup 1.0000x reference)
//
#include <hip/hip_runtime.h>
#include <hip/hip_bf16.h>

#define IN_F 4096

typedef __attribute__((ext_vector_type(8))) short short8;
typedef __attribute__((ext_vector_type(4))) float f32x4;
typedef __attribute__((ext_vector_type(4))) int int4v;
typedef __attribute__((ext_vector_type(4))) float float4v;

__device__ __forceinline__ ushort f2bf(float f) {
    unsigned u = __float_as_uint(f);
    unsigned r = (u + 0x7fffu + ((u >> 16) & 1u)) >> 16;
    return (ushort)r;
}

#define GLOAD_LDS16(gp, lp)                                            \
    __builtin_amdgcn_global_load_lds(                                  \
        (const __attribute__((address_space(1))) void*)(gp),           \
        (__attribute__((address_space(3))) void*)(lp), 16, 0, 0)

// ---------------- prep kernels ----------------

__global__ void cvt_x_kernel(const float* __restrict__ x,
                             ushort* __restrict__ o, long n) {
    long i = ((long)blockIdx.x * blockDim.x + threadIdx.x) * 8;
    if (i >= n) return;
    float4v a = *(const float4v*)(x + i);
    float4v b = *(const float4v*)(x + i + 4);
    short8 r;
    r[0] = (short)f2bf(a.x); r[1] = (short)f2bf(a.y);
    r[2] = (short)f2bf(a.z); r[3] = (short)f2bf(a.w);
    r[4] = (short)f2bf(b.x); r[5] = (short)f2bf(b.y);
    r[6] = (short)f2bf(b.z); r[7] = (short)f2bf(b.w);
    *(short8*)(o + i) = r;
}

__global__ void dequant_kernel(const int* __restrict__ idx,
                               const float* __restrict__ cb,
                               ushort* __restrict__ w, long n) {
    __shared__ float cbs[256];
    if (threadIdx.x < 256) cbs[threadIdx.x] = cb[threadIdx.x];
    __syncthreads();
    long i = ((long)blockIdx.x * blockDim.x + threadIdx.x) * 8;
    if (i >= n) return;
    int4v a = *(const int4v*)(idx + i);
    int4v b = *(const int4v*)(idx + i + 4);
    short8 r;
    r[0] = (short)f2bf(cbs[a.x]); r[1] = (short)f2bf(cbs[a.y]);
    r[2] = (short)f2bf(cbs[a.z]); r[3] = (short)f2bf(cbs[a.w]);
    r[4] = (short)f2bf(cbs[b.x]); r[5] = (short)f2bf(cbs[b.y]);
    r[6] = (short)f2bf(cbs[b.z]); r[7] = (short)f2bf(cbs[b.w]);
    *(short8*)(w + i) = r;
}

// ---------------- main GEMM (m97-style 128x128, BK=64) ----------------
// A [M][K] bf16 (x), B [N][K] bf16 (dequantized W), C [M][N] f32 = A·B^T + bias

#define BM 128
#define BN 128
#define BK 64

__global__ __launch_bounds__(256, 2) void gemm_bt(
    const ushort* __restrict__ A, const ushort* __restrict__ B,
    const float* __restrict__ bias, float* __restrict__ C,
    int M, int N, int K) {
    __shared__ ushort As[BM * BK];  // 16 KB, swizzled layout
    __shared__ ushort Bs[BN * BK];  // 16 KB

    const int nbx = N / BN;
    const int nwg = (M / BM) * nbx;
    int bid = blockIdx.x;
    // T1: XCD-aware swizzle (valid: nwg % 8 == 0 for 8192x11008)
    int swz = ((nwg & 7) == 0) ? ((bid & 7) * (nwg >> 3) + (bid >> 3)) : bid;
    const int bx = swz % nbx;
    const int by = swz / nbx;

    const int t = threadIdx.x;
    const int lane = t & 63;
    const int wave = t >> 6;
    const int wr = wave >> 1;   // wave row (0..1), 64 rows each
    const int wc = wave & 1;    // wave col (0..1), 64 cols each

    const size_t Abase = (size_t)by * BM * K;
    const size_t Bbase = (size_t)bx * BN * K;

    f32x4 acc[4][4];
#pragma unroll
    for (int m = 0; m < 4; ++m)
#pragma unroll
        for (int n = 0; n < 4; ++n) acc[m][n] = (f32x4){0.f, 0.f, 0.f, 0.f};

    for (int kt = 0; kt < K; kt += BK) {
        // ---- stage A and B tiles: linear LDS dest, inverse-swizzled global src
#pragma unroll
        for (int j = 0; j < 4; ++j) {
            int P = j * 4096 + t * 16;           // physical LDS byte
            int r = P >> 7;                      // row (128 B per row)
            int kb = P & 127;                    // physical k-byte
            int kbs = kb ^ ((r & 7) << 4);       // element k-byte (involution)
            const ushort* ga = A + Abase + (size_t)r * K + kt + (kbs >> 1);
            GLOAD_LDS16(ga, (char*)As + P);
        }
#pragma unroll
        for (int j = 0; j < 4; ++j) {
            int P = j * 4096 + t * 16;
            int r = P >> 7;
            int kb = P & 127;
            int kbs = kb ^ ((r & 7) << 4);
            const ushort* gb = B + Bbase + (size_t)r * K + kt + (kbs >> 1);
            GLOAD_LDS16(gb, (char*)Bs + P);
        }
        __syncthreads();  // drains vmcnt(0) + barrier

#pragma unroll
        for (int kk = 0; kk < 2; ++kk) {
            short8 af[4], bf[4];
            const int kbyte = kk * 64 + ((lane >> 4) << 4);
#pragma unroll
            for (int m = 0; m < 4; ++m) {
                int row = wr * 64 + m * 16 + (lane & 15);
                int phys = row * 128 + (kbyte ^ ((row & 7) << 4));
                af[m] = *(const short8*)((const char*)As + phys);
            }
#pragma unroll
            for (int n = 0; n < 4; ++n) {
                int row = wc * 64 + n * 16 + (lane & 15);
                int phys = row * 128 + (kbyte ^ ((row & 7) << 4));
                bf[n] = *(const short8*)((const char*)Bs + phys);
            }
#pragma unroll
            for (int m = 0; m < 4; ++m)
#pragma unroll
                for (int n = 0; n < 4; ++n)
                    acc[m][n] = __builtin_amdgcn_mfma_f32_16x16x32_bf16(
                        af[m], bf[n], acc[m][n], 0, 0, 0);
        }
        __syncthreads();  // compute done before next stage overwrites
    }

    // ---- epilogue: C = acc + bias
    const int colB = bx * BN + wc * 64 + (lane & 15);
    const int rowB = by * BM + wr * 64 + ((lane >> 4) << 2);
    float bv[4];
#pragma unroll
    for (int n = 0; n < 4; ++n) bv[n] = bias[colB + n * 16];
#pragma unroll
    for (int m = 0; m < 4; ++m) {
        int row0 = rowB + m * 16;
#pragma unroll
        for (int n = 0; n < 4; ++n) {
            int col = colB + n * 16;
#pragma unroll
            for (int j = 0; j < 4; ++j)
                C[(size_t)(row0 + j) * N + col] = acc[m][n][j] + bv[n];
        }
    }
}

// ---------------- fallback (ws too small / odd dims): slow but correct ----
__global__ void fallback_gemm(const float* __restrict__ x,
                              const int* __restrict__ widx,
                              const float* __restrict__ cb,
                              const float* __restrict__ bias,
                              float* __restrict__ out, long total, int N,
                              int K) {
    __shared__ float cbs[256];
    if (threadIdx.x < 256) cbs[threadIdx.x] = cb[threadIdx.x];
    __syncthreads();
    for (long i = (long)blockIdx.x * 256 + threadIdx.x; i < total;
         i += (long)gridDim.x * 256) {
        long nrow = i / N;
        int o = (int)(i - nrow * N);
        const float* xr = x + nrow * K;
        const int* ir = widx + (long)o * K;
        float s = 0.f;
        for (int k = 0; k < K; ++k) s += xr[k] * cbs[ir[k]];
        out[i] = s + bias[o];
    }
}

extern "C" void kernel_launch(void* const* d_in, const int* in_sizes, int n_in,
                              void* d_out, int out_size, void* d_ws,
                              size_t ws_size, hipStream_t stream) {
    const float* x = (const float*)d_in[0];
    const int* widx = (const int*)d_in[1];
    const float* cb = (const float*)d_in[2];
    const float* bias = (const float*)d_in[3];
    float* out = (float*)d_out;

    const long xcount = in_sizes[0];   // Mtok * K
    const long wcount = in_sizes[1];   // N * K
    const int K = IN_F;
    const int N = in_sizes[3];
    const long Mtok = xcount / K;

    const size_t xbytes = (size_t)xcount * 2;
    const size_t wbytes = (size_t)wcount * 2;

    const bool fast = (ws_size >= xbytes + wbytes) && (Mtok % BM == 0) &&
                      (N % BN == 0) && (K % BK == 0) && (xcount % 2048 == 0) &&
                      (wcount % 2048 == 0);

    if (fast) {
        ushort* xb = (ushort*)d_ws;
        ushort* wb = (ushort*)((char*)d_ws + xbytes);
        cvt_x_kernel<<<(int)(xcount / 8 / 256), 256, 0, stream>>>(x, xb, xcount);
        dequant_kernel<<<(int)(wcount / 8 / 256), 256, 0, stream>>>(widx, cb, wb,
                                                                    wcount);
        const int nwg = (int)(Mtok / BM) * (N / BN);
        gemm_bt<<<nwg, 256, 0, stream>>>(xb, wb, bias, out, (int)Mtok, N, K);
    } else {
        const long total = Mtok * (long)N;
        fallback_gemm<<<2048, 256, 0, stream>>>(x, widx, cb, bias, out, total,
                                                N, K);
    }
}